// Round 2
// baseline (912.053 us; speedup 1.0000x reference)
//
#include <hip/hip_runtime.h>

#define NPTS 4096
#define NQ   1024     // S
#define NB   16       // B
#define KNN  32
#define MROWS 524288  // B*S*K
#define FLT_MAX_ 3.402823466e+38f

// ---------- bf16 helpers (manual, RNE) ----------
__device__ inline unsigned short f2bf(float x){
  unsigned u = __float_as_uint(x);
  u += 0x7fffu + ((u >> 16) & 1u);
  return (unsigned short)(u >> 16);
}
__device__ inline float bf2f(unsigned v){           // low 16 bits used
  return __uint_as_float(v << 16);
}
__device__ inline unsigned pk2(float a, float b){
  return (unsigned)f2bf(a) | ((unsigned)f2bf(b) << 16);
}

// ---------- Kernel 1: top-K=32 nearest neighbors, one wave per query ----------
// Block 0 also zeroes the stats accumulators (512 floats).
__global__ __launch_bounds__(256) void topk_kernel(const float* __restrict__ xyz,
                                                   int* __restrict__ idx_out,
                                                   float* __restrict__ statsacc){
  __shared__ float xs[NPTS], ys[NPTS], zs[NPTS];
  const int tid = threadIdx.x;
  if (blockIdx.x == 0){
    for (int i = tid; i < 512; i += 256) statsacc[i] = 0.f;
  }
  const int b = blockIdx.x >> 8;            // 256 blocks per batch (4 queries/block)
  const float* xb = xyz + (size_t)b * NPTS * 3;
  for (int p = tid; p < NPTS; p += 256){
    xs[p] = xb[3*p + 0];
    ys[p] = xb[3*p + 1];
    zs[p] = xb[3*p + 2];
  }
  __syncthreads();

  const int w    = tid >> 6;
  const int lane = tid & 63;
  const int q    = (blockIdx.x << 2) + w;   // global query id
  const int s    = q & (NQ - 1);

  const float qx = xs[s], qy = ys[s], qz = zs[s];
  const float src2 = (qx*qx + qy*qy) + qz*qz;

  float c0 = FLT_MAX_, c1 = FLT_MAX_, c2 = FLT_MAX_, c3 = FLT_MAX_;
  int   i0 = -1, i1 = -1, i2 = -1, i3 = -1;
  unsigned long long consumed = 0ull;

  #pragma unroll 4
  for (int e = 0; e < 64; ++e){
    const int j = (e << 6) | lane;
    const float px = xs[j], py = ys[j], pz = zs[j];
    const float dst2 = (px*px + py*py) + pz*pz;
    const float dot  = (qx*px + qy*py) + qz*pz;
    const float d = -2.f*dot + src2 + dst2;
    if (d < c3){
      c3 = d; i3 = j;
      if (c3 < c2){ float t=c2; c2=c3; c3=t; int u=i2; i2=i3; i3=u; }
      if (c2 < c1){ float t=c1; c1=c2; c2=t; int u=i1; i1=i2; i2=u; }
      if (c1 < c0){ float t=c0; c0=c1; c1=t; int u=i0; i0=i1; i1=u; }
    }
  }
  int ncache = 4;
  int* outq = idx_out + q * KNN;

  for (int it = 0; it < KNN; ++it){
    float cand = c0; int candidx = i0;
    #pragma unroll
    for (int m = 32; m >= 1; m >>= 1){
      float od = __shfl_xor(cand, m, 64);
      int   oi = __shfl_xor(candidx, m, 64);
      if (od < cand || (od == cand && (unsigned)oi < (unsigned)candidx)){ cand = od; candidx = oi; }
    }
    if (lane == 0) outq[it] = candidx;
    if (i0 == candidx){
      consumed |= (1ull << (candidx >> 6));
      c0=c1; i0=i1; c1=c2; i1=i2; c2=c3; i2=i3; c3=FLT_MAX_; i3=-1;
      if (--ncache == 0){
        c0=c1=c2=c3=FLT_MAX_; i0=i1=i2=i3=-1;
        for (int e = 0; e < 64; ++e){
          if ((consumed >> e) & 1ull) continue;
          const int j = (e << 6) | lane;
          const float px = xs[j], py = ys[j], pz = zs[j];
          const float dst2 = (px*px + py*py) + pz*pz;
          const float dot  = (qx*px + qy*py) + qz*pz;
          const float d = -2.f*dot + src2 + dst2;
          if (d < c3){
            c3 = d; i3 = j;
            if (c3 < c2){ float t=c2; c2=c3; c3=t; int u=i2; i2=i3; i3=u; }
            if (c2 < c1){ float t=c1; c1=c2; c2=t; int u=i1; i1=i2; i2=u; }
            if (c1 < c0){ float t=c0; c0=c1; c1=t; int u=i0; i0=i1; i1=u; }
          }
        }
        ncache = 4;
      }
    }
  }
}

// ---------- Kernel 2: gather + concat + layer0 GEMM (67 -> 64), h0 in bf16 ----------
__global__ __launch_bounds__(256) void l0_kernel(const float* __restrict__ xyz,
                                                 const float* __restrict__ pts,
                                                 const int*   __restrict__ idxbuf,
                                                 const float* __restrict__ W,    // (64,67)
                                                 const float* __restrict__ bias, // (64)
                                                 uint4* __restrict__ hout){
  const int row = blockIdx.x * 256 + threadIdx.x;
  const int q = row >> 5;
  const int b = q >> 10, s = q & 1023;
  const int j = idxbuf[row];

  const float* qp = xyz + ((size_t)b * NPTS + s) * 3;
  const float* np_ = xyz + ((size_t)b * NPTS + j) * 3;
  float f[67];
  f[0] = np_[0] - qp[0];
  f[1] = np_[1] - qp[1];
  f[2] = np_[2] - qp[2];
  const float4* p4 = (const float4*)(pts + ((size_t)b * NPTS + j) * 64);
  #pragma unroll
  for (int u = 0; u < 16; ++u){
    float4 v = p4[u];
    f[3 + 4*u] = v.x; f[4 + 4*u] = v.y; f[5 + 4*u] = v.z; f[6 + 4*u] = v.w;
  }

  uint4* orow = hout + (size_t)row * 8;
  for (int ocb = 0; ocb < 4; ++ocb){
    float h[16];
    #pragma unroll
    for (int oc = 0; oc < 16; ++oc) h[oc] = bias[ocb*16 + oc];
    #pragma unroll
    for (int c = 0; c < 67; ++c){
      const float fc = f[c];
      #pragma unroll
      for (int oc = 0; oc < 16; ++oc)
        h[oc] = fmaf(W[(ocb*16 + oc)*67 + c], fc, h[oc]);
    }
    uint4 o0, o1;
    o0.x = pk2(h[0],h[1]);   o0.y = pk2(h[2],h[3]);   o0.z = pk2(h[4],h[5]);   o0.w = pk2(h[6],h[7]);
    o1.x = pk2(h[8],h[9]);   o1.y = pk2(h[10],h[11]); o1.z = pk2(h[12],h[13]); o1.w = pk2(h[14],h[15]);
    orow[ocb*2 + 0] = o0;
    orow[ocb*2 + 1] = o1;
  }
}

// ---------- Layer 1: normalize(relu) input + GEMM 64->64 ----------
__global__ __launch_bounds__(256) void l1_kernel(const uint4* __restrict__ hin,
                                                 const float* __restrict__ ss,   // (64,2) scale,shift
                                                 const float* __restrict__ W,    // (64,64)
                                                 const float* __restrict__ bias, // (64)
                                                 uint4* __restrict__ hout){
  const int row = blockIdx.x * 256 + threadIdx.x;
  float f[64];
  const uint4* hr = hin + (size_t)row * 8;
  #pragma unroll
  for (int u = 0; u < 8; ++u){
    uint4 v = hr[u];
    const unsigned wv[4] = {v.x, v.y, v.z, v.w};
    #pragma unroll
    for (int t = 0; t < 4; ++t){
      const int c = u*8 + t*2;
      f[c+0] = fmaxf(fmaf(bf2f(wv[t] & 0xffffu), ss[2*(c+0)], ss[2*(c+0)+1]), 0.f);
      f[c+1] = fmaxf(fmaf(bf2f(wv[t] >> 16),     ss[2*(c+1)], ss[2*(c+1)+1]), 0.f);
    }
  }
  uint4* orow = hout + (size_t)row * 8;
  for (int ocb = 0; ocb < 4; ++ocb){
    float h[16];
    #pragma unroll
    for (int oc = 0; oc < 16; ++oc) h[oc] = bias[ocb*16 + oc];
    #pragma unroll
    for (int c = 0; c < 64; ++c){
      const float fc = f[c];
      #pragma unroll
      for (int oc = 0; oc < 16; ++oc)
        h[oc] = fmaf(W[(ocb*16 + oc)*64 + c], fc, h[oc]);
    }
    uint4 o0, o1;
    o0.x = pk2(h[0],h[1]);   o0.y = pk2(h[2],h[3]);   o0.z = pk2(h[4],h[5]);   o0.w = pk2(h[6],h[7]);
    o1.x = pk2(h[8],h[9]);   o1.y = pk2(h[10],h[11]); o1.z = pk2(h[12],h[13]); o1.w = pk2(h[14],h[15]);
    orow[ocb*2 + 0] = o0;
    orow[ocb*2 + 1] = o1;
  }
}

// ---------- Layer 2: normalize(relu) + GEMM 64->128, SPLIT output ----------
// lo/hi alias h0/h1 regions. hin row is read fully before stores (full data
// dependency); pointers intentionally NOT __restrict__ (hi aliases hin).
__global__ __launch_bounds__(256) void l2_kernel(const uint4* hin,
                                                 const float* __restrict__ ss,
                                                 const float* __restrict__ W,    // (128,64)
                                                 const float* __restrict__ bias, // (128)
                                                 uint4* lo, uint4* hi){
  const int row = blockIdx.x * 256 + threadIdx.x;
  float f[64];
  const uint4* hr = hin + (size_t)row * 8;
  #pragma unroll
  for (int u = 0; u < 8; ++u){
    uint4 v = hr[u];
    const unsigned wv[4] = {v.x, v.y, v.z, v.w};
    #pragma unroll
    for (int t = 0; t < 4; ++t){
      const int c = u*8 + t*2;
      f[c+0] = fmaxf(fmaf(bf2f(wv[t] & 0xffffu), ss[2*(c+0)], ss[2*(c+0)+1]), 0.f);
      f[c+1] = fmaxf(fmaf(bf2f(wv[t] >> 16),     ss[2*(c+1)], ss[2*(c+1)+1]), 0.f);
    }
  }
  uint4* orow_lo = lo + (size_t)row * 8;
  uint4* orow_hi = hi + (size_t)row * 8;
  for (int ocb = 0; ocb < 8; ++ocb){
    float h[16];
    #pragma unroll
    for (int oc = 0; oc < 16; ++oc) h[oc] = bias[ocb*16 + oc];
    #pragma unroll
    for (int c = 0; c < 64; ++c){
      const float fc = f[c];
      #pragma unroll
      for (int oc = 0; oc < 16; ++oc)
        h[oc] = fmaf(W[(ocb*16 + oc)*64 + c], fc, h[oc]);
    }
    uint4 o0, o1;
    o0.x = pk2(h[0],h[1]);   o0.y = pk2(h[2],h[3]);   o0.z = pk2(h[4],h[5]);   o0.w = pk2(h[6],h[7]);
    o1.x = pk2(h[8],h[9]);   o1.y = pk2(h[10],h[11]); o1.z = pk2(h[12],h[13]); o1.w = pk2(h[14],h[15]);
    if (ocb < 4){
      orow_lo[ocb*2 + 0] = o0;
      orow_lo[ocb*2 + 1] = o1;
    } else {
      orow_hi[(ocb-4)*2 + 0] = o0;
      orow_hi[(ocb-4)*2 + 1] = o1;
    }
  }
}

// ---------- Stats: sum + sumsq over all rows, 64 channels ----------
__global__ __launch_bounds__(256) void stats_sum_kernel(const unsigned* __restrict__ hin,
                                                        float* __restrict__ acc){
  constexpr int PAIRS = 32;
  constexpr int RPI = 8;                    // rows per iteration per block
  constexpr int ROWS_PER_BLOCK = MROWS/512;
  __shared__ float sacc[128];
  const int tid = threadIdx.x;
  for (int i = tid; i < 128; i += 256) sacc[i] = 0.f;
  __syncthreads();
  const int cp = tid & (PAIRS-1);
  const int ro = tid / PAIRS;
  float s0=0.f, q0=0.f, s1=0.f, q1=0.f;
  const size_t base = (size_t)blockIdx.x * ROWS_PER_BLOCK;
  for (int it = 0; it < ROWS_PER_BLOCK/RPI; ++it){
    unsigned v = hin[(base + it*RPI + ro) * PAIRS + cp];
    float a = bf2f(v & 0xffffu), b = bf2f(v >> 16);
    s0 += a; q0 += a*a; s1 += b; q1 += b*b;
  }
  atomicAdd(&sacc[2*cp + 0], s0);
  atomicAdd(&sacc[2*cp + 1], s1);
  atomicAdd(&sacc[64 + 2*cp + 0], q0);
  atomicAdd(&sacc[64 + 2*cp + 1], q1);
  __syncthreads();
  for (int i = tid; i < 128; i += 256) atomicAdd(&acc[i], sacc[i]);
}

// acc layout: [0..63]=sum, [64..127]=sumsq (64 channels)
__global__ void stats_fin_kernel(const float* __restrict__ acc,
                                 const float* __restrict__ g,
                                 const float* __restrict__ be,
                                 float* __restrict__ ss){
  const int c = threadIdx.x;
  if (c < 64){
    const float invM = 1.f / (float)MROWS;
    const float mean = acc[c] * invM;
    const float var  = acc[64 + c] * invM - mean*mean;
    const float istd = rsqrtf(var + 1e-5f);
    const float scale = g[c] * istd;
    ss[2*c + 0] = scale;
    ss[2*c + 1] = be[c] - mean * scale;
  }
}

// ---------- Final: normalize+relu h2 (split halves), max over K, write out ----------
__global__ __launch_bounds__(256) void final_kernel(const float* __restrict__ xyz,
                                                    const unsigned* __restrict__ lo,
                                                    const unsigned* __restrict__ hi,
                                                    const float* __restrict__ ss,
                                                    float* __restrict__ out){
  const int q = blockIdx.x * 4 + (threadIdx.x >> 6);
  const int p = threadIdx.x & 63;          // channel pair 0..63 (128 channels)
  const float sc0 = ss[4*p + 0], sh0 = ss[4*p + 1];
  const float sc1 = ss[4*p + 2], sh1 = ss[4*p + 3];
  // each half-row is 32 u32; rows of query q are k=0..31
  const unsigned* src = (p < 32) ? (lo + (size_t)q*32*32 + p)
                                 : (hi + (size_t)q*32*32 + (p - 32));
  float m0 = -FLT_MAX_, m1 = -FLT_MAX_;
  #pragma unroll 4
  for (int k = 0; k < 32; ++k){
    unsigned v = src[k*32];
    float a = fmaxf(fmaf(bf2f(v & 0xffffu), sc0, sh0), 0.f);
    float b = fmaxf(fmaf(bf2f(v >> 16),     sc1, sh1), 0.f);
    m0 = fmaxf(m0, a);
    m1 = fmaxf(m1, b);
  }
  float2 r; r.x = m0; r.y = m1;
  ((float2*)(out + (size_t)NB*NQ*3))[(size_t)q*64 + p] = r;
  if (p < 3){
    const int b_ = q >> 10, s = q & 1023;
    out[(size_t)q*3 + p] = xyz[((size_t)b_ * NPTS + s)*3 + p];
  }
}

// ---------- host ----------
extern "C" void kernel_launch(void* const* d_in, const int* in_sizes, int n_in,
                              void* d_out, int out_size, void* d_ws, size_t ws_size,
                              hipStream_t stream){
  (void)in_sizes; (void)n_in; (void)out_size; (void)ws_size;
  const float* xyz = (const float*)d_in[0];
  const float* pts = (const float*)d_in[1];
  const float* W0  = (const float*)d_in[2];
  const float* b0  = (const float*)d_in[3];
  const float* g0  = (const float*)d_in[4];
  const float* be0 = (const float*)d_in[5];
  const float* W1  = (const float*)d_in[6];
  const float* b1  = (const float*)d_in[7];
  const float* g1  = (const float*)d_in[8];
  const float* be1 = (const float*)d_in[9];
  const float* W2  = (const float*)d_in[10];
  const float* b2  = (const float*)d_in[11];
  const float* g2  = (const float*)d_in[12];
  const float* be2 = (const float*)d_in[13];

  // workspace layout (total ~130.0 MB):
  //   [0, 2MB)                 idx (MROWS int32)
  //   [2MB, +2KB)              acc: acc0(128) acc1(128) acc2lo(128) acc2hi(128)
  //   [.., +2KB)               ss:  ss0(128)  ss1(128)  ss2(256)
  //   [2101248, +64MB)         h0  (also h2 lo-half later)
  //   [+64MB, +64MB)           h1  (also h2 hi-half later)
  char* ws = (char*)d_ws;
  int*   idx = (int*)ws;
  float* acc = (float*)(ws + 2097152);          // 512 floats
  float* ss  = (float*)(ws + 2097152 + 2048);   // 512 floats
  unsigned* h0 = (unsigned*)(ws + 2101248);
  unsigned* h1 = (unsigned*)(ws + 2101248 + 67108864);
  float* out = (float*)d_out;

  float* acc0 = acc, *acc1 = acc + 128, *acc2lo = acc + 256, *acc2hi = acc + 384;
  float* ss0 = ss, *ss1 = ss + 128, *ss2 = ss + 256;

  topk_kernel<<<4096, 256, 0, stream>>>(xyz, idx, acc);
  l0_kernel<<<2048, 256, 0, stream>>>(xyz, pts, idx, W0, b0, (uint4*)h0);
  stats_sum_kernel<<<512, 256, 0, stream>>>(h0, acc0);
  stats_fin_kernel<<<1, 64, 0, stream>>>(acc0, g0, be0, ss0);
  l1_kernel<<<2048, 256, 0, stream>>>((const uint4*)h0, ss0, W1, b1, (uint4*)h1);
  stats_sum_kernel<<<512, 256, 0, stream>>>(h1, acc1);
  stats_fin_kernel<<<1, 64, 0, stream>>>(acc1, g1, be1, ss1);
  // h2: lo half overwrites h0 (dead), hi half overwrites h1 row-after-read
  l2_kernel<<<2048, 256, 0, stream>>>((const uint4*)h1, ss1, W2, b2, (uint4*)h0, (uint4*)h1);
  stats_sum_kernel<<<512, 256, 0, stream>>>(h0, acc2lo);
  stats_sum_kernel<<<512, 256, 0, stream>>>(h1, acc2hi);
  stats_fin_kernel<<<1, 64, 0, stream>>>(acc2lo, g2, be2, ss2);
  stats_fin_kernel<<<1, 64, 0, stream>>>(acc2hi, g2 + 64, be2 + 64, ss2 + 128);
  final_kernel<<<4096, 256, 0, stream>>>(xyz, h0, h1, ss2, out);
}

// Round 3
// 454.468 us; speedup vs baseline: 2.0069x; 2.0069x over previous
//
#include <hip/hip_runtime.h>

#define NPTS 4096
#define NQ   1024     // S
#define NB   16       // B
#define KNN  32
#define MROWS 524288  // B*S*K
#define FLT_MAX_ 3.402823466e+38f

typedef __attribute__((ext_vector_type(8))) short short8;
typedef __attribute__((ext_vector_type(4))) float f32x4;

// ---------- bf16 helpers (manual, RNE) ----------
__device__ inline unsigned short f2bf(float x){
  unsigned u = __float_as_uint(x);
  u += 0x7fffu + ((u >> 16) & 1u);
  return (unsigned short)(u >> 16);
}
__device__ inline float bf2f(unsigned v){           // low 16 bits used
  return __uint_as_float(v << 16);
}

// normalize+relu 8 bf16 (one A-fragment k-slice) -> bf16 frag
__device__ inline short8 norm_frag(uint4 v, const float* sc, const float* sh){
  short8 r;
  const unsigned u[4] = {v.x, v.y, v.z, v.w};
  #pragma unroll
  for (int i = 0; i < 8; ++i){
    const unsigned raw = (i & 1) ? (u[i >> 1] >> 16) : (u[i >> 1] & 0xffffu);
    const float f = fmaxf(fmaf(bf2f(raw), sc[i], sh[i]), 0.f);
    r[i] = (short)f2bf(f);
  }
  return r;
}

// ---------- Kernel 1: top-K=32 nearest neighbors, one wave per query ----------
// Block 0 also zeroes the stats accumulators (512 floats).
__global__ __launch_bounds__(256) void topk_kernel(const float* __restrict__ xyz,
                                                   int* __restrict__ idx_out,
                                                   float* __restrict__ statsacc){
  __shared__ float xs[NPTS], ys[NPTS], zs[NPTS];
  const int tid = threadIdx.x;
  if (blockIdx.x == 0){
    for (int i = tid; i < 512; i += 256) statsacc[i] = 0.f;
  }
  const int b = blockIdx.x >> 8;            // 256 blocks per batch (4 queries/block)
  const float* xb = xyz + (size_t)b * NPTS * 3;
  for (int p = tid; p < NPTS; p += 256){
    xs[p] = xb[3*p + 0];
    ys[p] = xb[3*p + 1];
    zs[p] = xb[3*p + 2];
  }
  __syncthreads();

  const int w    = tid >> 6;
  const int lane = tid & 63;
  const int q    = (blockIdx.x << 2) + w;   // global query id
  const int s    = q & (NQ - 1);

  const float qx = xs[s], qy = ys[s], qz = zs[s];
  const float src2 = (qx*qx + qy*qy) + qz*qz;

  float c0 = FLT_MAX_, c1 = FLT_MAX_, c2 = FLT_MAX_, c3 = FLT_MAX_;
  int   i0 = -1, i1 = -1, i2 = -1, i3 = -1;
  unsigned long long consumed = 0ull;

  #pragma unroll 4
  for (int e = 0; e < 64; ++e){
    const int j = (e << 6) | lane;
    const float px = xs[j], py = ys[j], pz = zs[j];
    const float dst2 = (px*px + py*py) + pz*pz;
    const float dot  = (qx*px + qy*py) + qz*pz;
    const float d = -2.f*dot + src2 + dst2;
    if (d < c3){
      c3 = d; i3 = j;
      if (c3 < c2){ float t=c2; c2=c3; c3=t; int u=i2; i2=i3; i3=u; }
      if (c2 < c1){ float t=c1; c1=c2; c2=t; int u=i1; i1=i2; i2=u; }
      if (c1 < c0){ float t=c0; c0=c1; c1=t; int u=i0; i0=i1; i1=u; }
    }
  }
  int ncache = 4;
  int* outq = idx_out + q * KNN;

  for (int it = 0; it < KNN; ++it){
    float cand = c0; int candidx = i0;
    #pragma unroll
    for (int m = 32; m >= 1; m >>= 1){
      float od = __shfl_xor(cand, m, 64);
      int   oi = __shfl_xor(candidx, m, 64);
      if (od < cand || (od == cand && (unsigned)oi < (unsigned)candidx)){ cand = od; candidx = oi; }
    }
    if (lane == 0) outq[it] = candidx;
    if (i0 == candidx){
      consumed |= (1ull << (candidx >> 6));
      c0=c1; i0=i1; c1=c2; i1=i2; c2=c3; i2=i3; c3=FLT_MAX_; i3=-1;
      if (--ncache == 0){
        c0=c1=c2=c3=FLT_MAX_; i0=i1=i2=i3=-1;
        for (int e = 0; e < 64; ++e){
          if ((consumed >> e) & 1ull) continue;
          const int j = (e << 6) | lane;
          const float px = xs[j], py = ys[j], pz = zs[j];
          const float dst2 = (px*px + py*py) + pz*pz;
          const float dot  = (qx*px + qy*py) + qz*pz;
          const float d = -2.f*dot + src2 + dst2;
          if (d < c3){
            c3 = d; i3 = j;
            if (c3 < c2){ float t=c2; c2=c3; c3=t; int u=i2; i2=i3; i3=u; }
            if (c2 < c1){ float t=c1; c1=c2; c2=t; int u=i1; i1=i2; i2=u; }
            if (c1 < c0){ float t=c0; c0=c1; c1=t; int u=i0; i0=i1; i1=u; }
          }
        }
        ncache = 4;
      }
    }
  }
}

// ---------- Layer 0: gather + concat + MFMA GEMM (K padded 67->96), fused stats ----------
// LDS tile: 256 rows x 104 ch (bf16), row stride 208B (2-way-bank-free).
// channel map: 0..63 = pts[j], 64..66 = dxyz, 67..95 = 0 (96..103 unused pad)
// W0pad[n][k] : k<64 -> W0[n][3+k] ; 64<=k<67 -> W0[n][k-64] ; else 0
__global__ __launch_bounds__(256) void l0_mfma(const float* __restrict__ xyz,
                                               const float* __restrict__ pts,
                                               const int*   __restrict__ idxbuf,
                                               const float* __restrict__ W,     // (64,67)
                                               const float* __restrict__ bias,  // (64)
                                               unsigned short* __restrict__ hout,
                                               float* __restrict__ acc){
  __shared__ short lds[256*104];
  __shared__ float sacc[128];
  const int tid = threadIdx.x;
  if (tid < 128) sacc[tid] = 0.f;
  const int lane = tid & 63, wv = tid >> 6;
  const int m16 = lane & 15, kg = lane >> 4;

  // B fragments + bias (per lane, n = ocb*16 + m16)
  short8 Bf[4][3];
  float  bl[4];
  for (int ocb = 0; ocb < 4; ++ocb){
    const int n = ocb*16 + m16;
    bl[ocb] = bias[n];
    for (int ks = 0; ks < 3; ++ks){
      short8 t;
      #pragma unroll
      for (int i = 0; i < 8; ++i){
        const int k = ks*32 + kg*8 + i;
        float wv_ = 0.f;
        if (k < 64) wv_ = W[n*67 + 3 + k];
        else if (k < 67) wv_ = W[n*67 + (k - 64)];
        t[i] = (short)f2bf(wv_);
      }
      Bf[ocb][ks] = t;
    }
  }

  // stage one row per thread
  {
    const int row = blockIdx.x*256 + tid;
    const int rowq = row >> 5;
    const int b = rowq >> 10, s = rowq & 1023;
    const int j = idxbuf[row];
    const float4* p4 = (const float4*)(pts + ((size_t)b*NPTS + j)*64);
    short* myrow = lds + tid*104;
    #pragma unroll
    for (int u = 0; u < 8; ++u){
      float4 x = p4[2*u], y = p4[2*u+1];
      short8 o;
      o[0]=(short)f2bf(x.x); o[1]=(short)f2bf(x.y); o[2]=(short)f2bf(x.z); o[3]=(short)f2bf(x.w);
      o[4]=(short)f2bf(y.x); o[5]=(short)f2bf(y.y); o[6]=(short)f2bf(y.z); o[7]=(short)f2bf(y.w);
      *(short8*)(myrow + u*8) = o;
    }
    const float* pj = xyz + ((size_t)b*NPTS + j)*3;
    const float* ps = xyz + ((size_t)b*NPTS + s)*3;
    short8 z = 0;
    z[0] = (short)f2bf(pj[0]-ps[0]);
    z[1] = (short)f2bf(pj[1]-ps[1]);
    z[2] = (short)f2bf(pj[2]-ps[2]);
    *(short8*)(myrow + 64) = z;
    short8 zz = 0;
    *(short8*)(myrow + 72) = zz;
    *(short8*)(myrow + 80) = zz;
    *(short8*)(myrow + 88) = zz;
  }
  __syncthreads();

  float sA[4] = {0,0,0,0}, qA[4] = {0,0,0,0};
  const int rowbase = blockIdx.x*256 + wv*64;
  for (int rt = 0; rt < 4; ++rt){
    const short* ar = lds + (wv*64 + rt*16 + m16)*104;
    short8 a0 = *(const short8*)(ar + kg*8);
    short8 a1 = *(const short8*)(ar + 32 + kg*8);
    short8 a2 = *(const short8*)(ar + 64 + kg*8);
    #pragma unroll
    for (int ocb = 0; ocb < 4; ++ocb){
      f32x4 c = {bl[ocb], bl[ocb], bl[ocb], bl[ocb]};
      c = __builtin_amdgcn_mfma_f32_16x16x32_bf16(a0, Bf[ocb][0], c, 0, 0, 0);
      c = __builtin_amdgcn_mfma_f32_16x16x32_bf16(a1, Bf[ocb][1], c, 0, 0, 0);
      c = __builtin_amdgcn_mfma_f32_16x16x32_bf16(a2, Bf[ocb][2], c, 0, 0, 0);
      #pragma unroll
      for (int r = 0; r < 4; ++r){
        const float hv = c[r];
        sA[ocb] += hv; qA[ocb] += hv*hv;
        const int orow = rowbase + rt*16 + kg*4 + r;
        hout[(size_t)orow*64 + ocb*16 + m16] = f2bf(hv);
      }
    }
  }
  #pragma unroll
  for (int ocb = 0; ocb < 4; ++ocb){
    float s = sA[ocb], q = qA[ocb];
    s += __shfl_xor(s, 16, 64); s += __shfl_xor(s, 32, 64);
    q += __shfl_xor(q, 16, 64); q += __shfl_xor(q, 32, 64);
    if (kg == 0){
      atomicAdd(&sacc[ocb*16 + m16], s);
      atomicAdd(&sacc[64 + ocb*16 + m16], q);
    }
  }
  __syncthreads();
  if (tid < 128) atomicAdd(&acc[tid], sacc[tid]);
}

// ---------- Layers 1,2: norm+relu(A) + MFMA GEMM (K=64), fused stats ----------
// OCB = COUT/16. SPLIT: ocb 0..3 -> out_lo, 4..7 -> out_hi (row-aliased with hin is
// safe: each wave fully loads its 16-row A-tile before the dependent stores).
template<int OCB, bool SPLIT>
__global__ __launch_bounds__(256) void l12_mfma(const unsigned* hin,
                                                const float* __restrict__ ss,    // (64,2)
                                                const float* __restrict__ W,     // (COUT,64)
                                                const float* __restrict__ bias,  // (COUT)
                                                unsigned short* out_lo,
                                                unsigned short* out_hi,
                                                float* __restrict__ acc){
  __shared__ float sacc[OCB*32];
  const int tid = threadIdx.x;
  for (int i = tid; i < OCB*32; i += 256) sacc[i] = 0.f;
  const int lane = tid & 63, wv = tid >> 6;
  const int m16 = lane & 15, kg = lane >> 4;

  // per-lane scale/shift for this lane's k channels
  float scl[2][8], shf[2][8];
  #pragma unroll
  for (int s2 = 0; s2 < 2; ++s2)
    #pragma unroll
    for (int i = 0; i < 8; ++i){
      const int c = s2*32 + kg*8 + i;
      scl[s2][i] = ss[2*c];
      shf[s2][i] = ss[2*c + 1];
    }

  short8 Bf[OCB][2];
  float  bl[OCB];
  for (int ocb = 0; ocb < OCB; ++ocb){
    const int n = ocb*16 + m16;
    bl[ocb] = bias[n];
    #pragma unroll
    for (int s2 = 0; s2 < 2; ++s2){
      short8 t;
      #pragma unroll
      for (int i = 0; i < 8; ++i)
        t[i] = (short)f2bf(W[n*64 + s2*32 + kg*8 + i]);
      Bf[ocb][s2] = t;
    }
  }
  __syncthreads();   // sacc zeroing visible before end-phase atomics

  float sA[OCB], qA[OCB];
  #pragma unroll
  for (int o = 0; o < OCB; ++o){ sA[o] = 0.f; qA[o] = 0.f; }

  const int rowbase = blockIdx.x*256 + wv*64;
  for (int rt = 0; rt < 4; ++rt){
    const int arow = rowbase + rt*16 + m16;
    const uint4* pr = (const uint4*)hin + (size_t)arow*8;
    uint4 v0 = pr[kg];
    uint4 v1 = pr[4 + kg];
    short8 a0 = norm_frag(v0, scl[0], shf[0]);
    short8 a1 = norm_frag(v1, scl[1], shf[1]);
    #pragma unroll
    for (int ocb = 0; ocb < OCB; ++ocb){
      f32x4 c = {bl[ocb], bl[ocb], bl[ocb], bl[ocb]};
      c = __builtin_amdgcn_mfma_f32_16x16x32_bf16(a0, Bf[ocb][0], c, 0, 0, 0);
      c = __builtin_amdgcn_mfma_f32_16x16x32_bf16(a1, Bf[ocb][1], c, 0, 0, 0);
      unsigned short* dst;
      int ncol;
      if (SPLIT){ dst = (ocb < 4) ? out_lo : out_hi; ncol = (ocb & 3)*16 + m16; }
      else      { dst = out_lo;                      ncol = ocb*16 + m16; }
      #pragma unroll
      for (int r = 0; r < 4; ++r){
        const float hv = c[r];
        sA[ocb] += hv; qA[ocb] += hv*hv;
        const int orow = rowbase + rt*16 + kg*4 + r;
        dst[(size_t)orow*64 + ncol] = f2bf(hv);
      }
    }
  }
  #pragma unroll
  for (int ocb = 0; ocb < OCB; ++ocb){
    float s = sA[ocb], q = qA[ocb];
    s += __shfl_xor(s, 16, 64); s += __shfl_xor(s, 32, 64);
    q += __shfl_xor(q, 16, 64); q += __shfl_xor(q, 32, 64);
    if (kg == 0){
      atomicAdd(&sacc[ocb*16 + m16], s);
      atomicAdd(&sacc[OCB*16 + ocb*16 + m16], q);
    }
  }
  __syncthreads();
  for (int i = tid; i < OCB*32; i += 256) atomicAdd(&acc[i], sacc[i]);
}

// acc layout: [0..C-1]=sum, [C..2C-1]=sumsq
__global__ void stats_fin_kernel(const float* __restrict__ acc,
                                 const float* __restrict__ g,
                                 const float* __restrict__ be,
                                 float* __restrict__ ss, int C){
  const int c = threadIdx.x;
  if (c < C){
    const float invM = 1.f / (float)MROWS;
    const float mean = acc[c] * invM;
    const float var  = acc[C + c] * invM - mean*mean;
    const float scale = g[c] * rsqrtf(var + 1e-5f);
    ss[2*c + 0] = scale;
    ss[2*c + 1] = be[c] - mean * scale;
  }
}

// ---------- Final: normalize+relu h2 (split halves), max over K, write out ----------
__global__ __launch_bounds__(256) void final_kernel(const float* __restrict__ xyz,
                                                    const unsigned* __restrict__ lo,
                                                    const unsigned* __restrict__ hi,
                                                    const float* __restrict__ ss,
                                                    float* __restrict__ out){
  const int q = blockIdx.x * 4 + (threadIdx.x >> 6);
  const int p = threadIdx.x & 63;          // channel pair 0..63 (128 channels)
  const float sc0 = ss[4*p + 0], sh0 = ss[4*p + 1];
  const float sc1 = ss[4*p + 2], sh1 = ss[4*p + 3];
  const unsigned* src = (p < 32) ? (lo + (size_t)q*32*32 + p)
                                 : (hi + (size_t)q*32*32 + (p - 32));
  float m0 = -FLT_MAX_, m1 = -FLT_MAX_;
  #pragma unroll 4
  for (int k = 0; k < 32; ++k){
    unsigned v = src[k*32];
    float a = fmaxf(fmaf(bf2f(v & 0xffffu), sc0, sh0), 0.f);
    float b = fmaxf(fmaf(bf2f(v >> 16),     sc1, sh1), 0.f);
    m0 = fmaxf(m0, a);
    m1 = fmaxf(m1, b);
  }
  float2 r; r.x = m0; r.y = m1;
  ((float2*)(out + (size_t)NB*NQ*3))[(size_t)q*64 + p] = r;
  if (p < 3){
    const int b_ = q >> 10, s = q & 1023;
    out[(size_t)q*3 + p] = xyz[((size_t)b_ * NPTS + s)*3 + p];
  }
}

// ---------- host ----------
extern "C" void kernel_launch(void* const* d_in, const int* in_sizes, int n_in,
                              void* d_out, int out_size, void* d_ws, size_t ws_size,
                              hipStream_t stream){
  (void)in_sizes; (void)n_in; (void)out_size; (void)ws_size;
  const float* xyz = (const float*)d_in[0];
  const float* pts = (const float*)d_in[1];
  const float* W0  = (const float*)d_in[2];
  const float* b0  = (const float*)d_in[3];
  const float* g0  = (const float*)d_in[4];
  const float* be0 = (const float*)d_in[5];
  const float* W1  = (const float*)d_in[6];
  const float* b1  = (const float*)d_in[7];
  const float* g1  = (const float*)d_in[8];
  const float* be1 = (const float*)d_in[9];
  const float* W2  = (const float*)d_in[10];
  const float* b2  = (const float*)d_in[11];
  const float* g2  = (const float*)d_in[12];
  const float* be2 = (const float*)d_in[13];

  // workspace: idx 2MB | acc 512f | ss 512f | h0 64MB (h2-lo later) | h1 64MB (h2-hi later)
  char* ws = (char*)d_ws;
  int*   idx = (int*)ws;
  float* acc = (float*)(ws + 2097152);
  float* ss  = (float*)(ws + 2097152 + 2048);
  unsigned* h0 = (unsigned*)(ws + 2101248);
  unsigned* h1 = (unsigned*)(ws + 2101248 + 67108864);
  float* out = (float*)d_out;

  float* acc0 = acc, *acc1 = acc + 128, *acc2 = acc + 256;   // acc2: 256 floats
  float* ss0 = ss, *ss1 = ss + 128, *ss2 = ss + 256;

  topk_kernel<<<4096, 256, 0, stream>>>(xyz, idx, acc);
  l0_mfma<<<2048, 256, 0, stream>>>(xyz, pts, idx, W0, b0, (unsigned short*)h0, acc0);
  stats_fin_kernel<<<1, 128, 0, stream>>>(acc0, g0, be0, ss0, 64);
  l12_mfma<4,false><<<2048, 256, 0, stream>>>(h0, ss0, W1, b1, (unsigned short*)h1, nullptr, acc1);
  stats_fin_kernel<<<1, 128, 0, stream>>>(acc1, g1, be1, ss1, 64);
  l12_mfma<8,true><<<2048, 256, 0, stream>>>(h1, ss1, W2, b2, (unsigned short*)h0, (unsigned short*)h1, acc2);
  stats_fin_kernel<<<1, 128, 0, stream>>>(acc2, g2, be2, ss2, 128);
  final_kernel<<<4096, 256, 0, stream>>>(xyz, h0, h1, ss2, out);
}

// Round 4
// 370.626 us; speedup vs baseline: 2.4608x; 1.2262x over previous
//
#include <hip/hip_runtime.h>

#define NPTS 4096
#define NQ   1024     // S
#define NB   16       // B
#define KNN  32
#define MROWS 524288  // B*S*K
#define FLT_MAX_ 3.402823466e+38f

typedef __attribute__((ext_vector_type(8))) short short8;
typedef __attribute__((ext_vector_type(4))) float f32x4;

// ---------- bf16 helpers (manual, RNE) ----------
__device__ inline unsigned short f2bf(float x){
  unsigned u = __float_as_uint(x);
  u += 0x7fffu + ((u >> 16) & 1u);
  return (unsigned short)(u >> 16);
}
__device__ inline float bf2f(unsigned v){           // low 16 bits used
  return __uint_as_float(v << 16);
}

// normalize+relu 8 bf16 (one A-fragment k-slice) -> bf16 frag
__device__ inline short8 norm_frag(uint4 v, const float* sc, const float* sh){
  short8 r;
  const unsigned u[4] = {v.x, v.y, v.z, v.w};
  #pragma unroll
  for (int i = 0; i < 8; ++i){
    const unsigned raw = (i & 1) ? (u[i >> 1] >> 16) : (u[i >> 1] & 0xffffu);
    const float f = fmaxf(fmaf(bf2f(raw), sc[i], sh[i]), 0.f);
    r[i] = (short)f2bf(f);
  }
  return r;
}

// ---------- Kernel 1: top-K=32 NN. 16 queries/block (16 waves), float4 LDS tile ----------
// Block 0 also zeroes the stats accumulators (512 floats).
__global__ __launch_bounds__(1024) void topk_kernel(const float* __restrict__ xyz,
                                                    int* __restrict__ idx_out,
                                                    float* __restrict__ statsacc){
  __shared__ float4 pbuf[NPTS];          // 64 KB: x,y,z,pad
  const int tid = threadIdx.x;
  if (blockIdx.x == 0 && tid < 512) statsacc[tid] = 0.f;

  const int b = blockIdx.x >> 6;         // 64 blocks per batch
  const float* xb = xyz + (size_t)b * NPTS * 3;
  for (int p = tid; p < NPTS; p += 1024){
    float4 v;
    v.x = xb[3*p + 0];
    v.y = xb[3*p + 1];
    v.z = xb[3*p + 2];
    v.w = 0.f;
    pbuf[p] = v;
  }
  __syncthreads();

  const int wv   = tid >> 6;
  const int lane = tid & 63;
  const int q    = (blockIdx.x << 4) + wv;   // global query id
  const int s    = q & (NQ - 1);

  const float4 qp = pbuf[s];
  const float qx = qp.x, qy = qp.y, qz = qp.z;
  const float src2 = (qx*qx + qy*qy) + qz*qz;

  float c0 = FLT_MAX_, c1 = FLT_MAX_, c2 = FLT_MAX_, c3 = FLT_MAX_;
  int   i0 = -1, i1 = -1, i2 = -1, i3 = -1;
  unsigned long long consumed = 0ull;

  #pragma unroll 4
  for (int e = 0; e < 64; ++e){
    const int j = (e << 6) | lane;
    const float4 pv = pbuf[j];
    const float px = pv.x, py = pv.y, pz = pv.z;
    const float dst2 = (px*px + py*py) + pz*pz;
    const float dot  = (qx*px + qy*py) + qz*pz;
    const float d = -2.f*dot + src2 + dst2;
    if (d < c3){
      c3 = d; i3 = j;
      if (c3 < c2){ float t=c2; c2=c3; c3=t; int u=i2; i2=i3; i3=u; }
      if (c2 < c1){ float t=c1; c1=c2; c2=t; int u=i1; i1=i2; i2=u; }
      if (c1 < c0){ float t=c0; c0=c1; c1=t; int u=i0; i0=i1; i1=u; }
    }
  }
  int ncache = 4;
  int mywin = 0;

  for (int it = 0; it < KNN; ++it){
    float cand = c0; int candidx = i0;
    #pragma unroll
    for (int m = 32; m >= 1; m >>= 1){
      float od = __shfl_xor(cand, m, 64);
      int   oi = __shfl_xor(candidx, m, 64);
      if (od < cand || (od == cand && (unsigned)oi < (unsigned)candidx)){ cand = od; candidx = oi; }
    }
    if (lane == it) mywin = candidx;
    if (i0 == candidx){
      consumed |= (1ull << (candidx >> 6));
      c0=c1; i0=i1; c1=c2; i1=i2; c2=c3; i2=i3; c3=FLT_MAX_; i3=-1;
      if (--ncache == 0){
        c0=c1=c2=c3=FLT_MAX_; i0=i1=i2=i3=-1;
        for (int e = 0; e < 64; ++e){
          if ((consumed >> e) & 1ull) continue;
          const int j = (e << 6) | lane;
          const float4 pv = pbuf[j];
          const float px = pv.x, py = pv.y, pz = pv.z;
          const float dst2 = (px*px + py*py) + pz*pz;
          const float dot  = (qx*px + qy*py) + qz*pz;
          const float d = -2.f*dot + src2 + dst2;
          if (d < c3){
            c3 = d; i3 = j;
            if (c3 < c2){ float t=c2; c2=c3; c3=t; int u=i2; i2=i3; i3=u; }
            if (c2 < c1){ float t=c1; c1=c2; c2=t; int u=i1; i1=i2; i2=u; }
            if (c1 < c0){ float t=c0; c0=c1; c1=t; int u=i0; i0=i1; i1=u; }
          }
        }
        ncache = 4;
      }
    }
  }
  if (lane < KNN) idx_out[q * KNN + lane] = mywin;
}

// ---------- Layer 0: gather + concat + MFMA GEMM (K padded 67->96), fused stats ----------
// LDS tile: 256 rows x 104 ch (bf16), row stride 208B.
// channel map: 0..63 = pts[j], 64..66 = dxyz, 67..95 = 0 (96..103 unused pad)
__global__ __launch_bounds__(256) void l0_mfma(const float* __restrict__ xyz,
                                               const float* __restrict__ pts,
                                               const int*   __restrict__ idxbuf,
                                               const float* __restrict__ W,     // (64,67)
                                               const float* __restrict__ bias,  // (64)
                                               unsigned short* __restrict__ hout,
                                               float* __restrict__ acc){
  __shared__ short lds[256*104];
  __shared__ float sacc[128];
  const int tid = threadIdx.x;
  if (tid < 128) sacc[tid] = 0.f;
  const int lane = tid & 63, wv = tid >> 6;
  const int m16 = lane & 15, kg = lane >> 4;

  // B fragments + bias (per lane, n = ocb*16 + m16)
  short8 Bf[4][3];
  float  bl[4];
  for (int ocb = 0; ocb < 4; ++ocb){
    const int n = ocb*16 + m16;
    bl[ocb] = bias[n];
    for (int ks = 0; ks < 3; ++ks){
      short8 t;
      #pragma unroll
      for (int i = 0; i < 8; ++i){
        const int k = ks*32 + kg*8 + i;
        float wv_ = 0.f;
        if (k < 64) wv_ = W[n*67 + 3 + k];
        else if (k < 67) wv_ = W[n*67 + (k - 64)];
        t[i] = (short)f2bf(wv_);
      }
      Bf[ocb][ks] = t;
    }
  }

  // stage one row per thread
  {
    const int row = blockIdx.x*256 + tid;
    const int rowq = row >> 5;
    const int b = rowq >> 10, s = rowq & 1023;
    const int j = idxbuf[row];
    const float4* p4 = (const float4*)(pts + ((size_t)b*NPTS + j)*64);
    short* myrow = lds + tid*104;
    #pragma unroll
    for (int u = 0; u < 8; ++u){
      float4 x = p4[2*u], y = p4[2*u+1];
      short8 o;
      o[0]=(short)f2bf(x.x); o[1]=(short)f2bf(x.y); o[2]=(short)f2bf(x.z); o[3]=(short)f2bf(x.w);
      o[4]=(short)f2bf(y.x); o[5]=(short)f2bf(y.y); o[6]=(short)f2bf(y.z); o[7]=(short)f2bf(y.w);
      *(short8*)(myrow + u*8) = o;
    }
    const float* pj = xyz + ((size_t)b*NPTS + j)*3;
    const float* ps = xyz + ((size_t)b*NPTS + s)*3;
    short8 z = 0;
    z[0] = (short)f2bf(pj[0]-ps[0]);
    z[1] = (short)f2bf(pj[1]-ps[1]);
    z[2] = (short)f2bf(pj[2]-ps[2]);
    *(short8*)(myrow + 64) = z;
    short8 zz = 0;
    *(short8*)(myrow + 72) = zz;
    *(short8*)(myrow + 80) = zz;
    *(short8*)(myrow + 88) = zz;
  }
  __syncthreads();

  float sA[4] = {0,0,0,0}, qA[4] = {0,0,0,0};
  const int rowbase = blockIdx.x*256 + wv*64;
  for (int rt = 0; rt < 4; ++rt){
    const short* ar = lds + (wv*64 + rt*16 + m16)*104;
    short8 a0 = *(const short8*)(ar + kg*8);
    short8 a1 = *(const short8*)(ar + 32 + kg*8);
    short8 a2 = *(const short8*)(ar + 64 + kg*8);
    #pragma unroll
    for (int ocb = 0; ocb < 4; ++ocb){
      f32x4 c = {bl[ocb], bl[ocb], bl[ocb], bl[ocb]};
      c = __builtin_amdgcn_mfma_f32_16x16x32_bf16(a0, Bf[ocb][0], c, 0, 0, 0);
      c = __builtin_amdgcn_mfma_f32_16x16x32_bf16(a1, Bf[ocb][1], c, 0, 0, 0);
      c = __builtin_amdgcn_mfma_f32_16x16x32_bf16(a2, Bf[ocb][2], c, 0, 0, 0);
      #pragma unroll
      for (int r = 0; r < 4; ++r){
        const float hv = c[r];
        sA[ocb] += hv; qA[ocb] += hv*hv;
        const int orow = rowbase + rt*16 + kg*4 + r;
        hout[(size_t)orow*64 + ocb*16 + m16] = f2bf(hv);
      }
    }
  }
  #pragma unroll
  for (int ocb = 0; ocb < 4; ++ocb){
    float s = sA[ocb], q = qA[ocb];
    s += __shfl_xor(s, 16, 64); s += __shfl_xor(s, 32, 64);
    q += __shfl_xor(q, 16, 64); q += __shfl_xor(q, 32, 64);
    if (kg == 0){
      atomicAdd(&sacc[ocb*16 + m16], s);
      atomicAdd(&sacc[64 + ocb*16 + m16], q);
    }
  }
  __syncthreads();
  if (tid < 128) atomicAdd(&acc[tid], sacc[tid]);
}

// ---------- Layers 1,2: norm+relu(A) + MFMA GEMM (K=64), fused stats ----------
template<int OCB, bool SPLIT>
__global__ __launch_bounds__(256) void l12_mfma(const unsigned* hin,
                                                const float* __restrict__ ss,    // (64,2)
                                                const float* __restrict__ W,     // (COUT,64)
                                                const float* __restrict__ bias,  // (COUT)
                                                unsigned short* out_lo,
                                                unsigned short* out_hi,
                                                float* __restrict__ acc){
  __shared__ float sacc[OCB*32];
  const int tid = threadIdx.x;
  for (int i = tid; i < OCB*32; i += 256) sacc[i] = 0.f;
  const int lane = tid & 63, wv = tid >> 6;
  const int m16 = lane & 15, kg = lane >> 4;

  float scl[2][8], shf[2][8];
  #pragma unroll
  for (int s2 = 0; s2 < 2; ++s2)
    #pragma unroll
    for (int i = 0; i < 8; ++i){
      const int c = s2*32 + kg*8 + i;
      scl[s2][i] = ss[2*c];
      shf[s2][i] = ss[2*c + 1];
    }

  short8 Bf[OCB][2];
  float  bl[OCB];
  for (int ocb = 0; ocb < OCB; ++ocb){
    const int n = ocb*16 + m16;
    bl[ocb] = bias[n];
    #pragma unroll
    for (int s2 = 0; s2 < 2; ++s2){
      short8 t;
      #pragma unroll
      for (int i = 0; i < 8; ++i)
        t[i] = (short)f2bf(W[n*64 + s2*32 + kg*8 + i]);
      Bf[ocb][s2] = t;
    }
  }
  __syncthreads();   // sacc zeroing visible before end-phase atomics

  float sA[OCB], qA[OCB];
  #pragma unroll
  for (int o = 0; o < OCB; ++o){ sA[o] = 0.f; qA[o] = 0.f; }

  const int rowbase = blockIdx.x*256 + wv*64;
  for (int rt = 0; rt < 4; ++rt){
    const int arow = rowbase + rt*16 + m16;
    const uint4* pr = (const uint4*)hin + (size_t)arow*8;
    uint4 v0 = pr[kg];
    uint4 v1 = pr[4 + kg];
    short8 a0 = norm_frag(v0, scl[0], shf[0]);
    short8 a1 = norm_frag(v1, scl[1], shf[1]);
    #pragma unroll
    for (int ocb = 0; ocb < OCB; ++ocb){
      f32x4 c = {bl[ocb], bl[ocb], bl[ocb], bl[ocb]};
      c = __builtin_amdgcn_mfma_f32_16x16x32_bf16(a0, Bf[ocb][0], c, 0, 0, 0);
      c = __builtin_amdgcn_mfma_f32_16x16x32_bf16(a1, Bf[ocb][1], c, 0, 0, 0);
      unsigned short* dst;
      int ncol;
      if (SPLIT){ dst = (ocb < 4) ? out_lo : out_hi; ncol = (ocb & 3)*16 + m16; }
      else      { dst = out_lo;                      ncol = ocb*16 + m16; }
      #pragma unroll
      for (int r = 0; r < 4; ++r){
        const float hv = c[r];
        sA[ocb] += hv; qA[ocb] += hv*hv;
        const int orow = rowbase + rt*16 + kg*4 + r;
        dst[(size_t)orow*64 + ncol] = f2bf(hv);
      }
    }
  }
  #pragma unroll
  for (int ocb = 0; ocb < OCB; ++ocb){
    float s = sA[ocb], q = qA[ocb];
    s += __shfl_xor(s, 16, 64); s += __shfl_xor(s, 32, 64);
    q += __shfl_xor(q, 16, 64); q += __shfl_xor(q, 32, 64);
    if (kg == 0){
      atomicAdd(&sacc[ocb*16 + m16], s);
      atomicAdd(&sacc[OCB*16 + ocb*16 + m16], q);
    }
  }
  __syncthreads();
  for (int i = tid; i < OCB*32; i += 256) atomicAdd(&acc[i], sacc[i]);
}

// acc layout: [0..C-1]=sum, [C..2C-1]=sumsq
__global__ void stats_fin_kernel(const float* __restrict__ acc,
                                 const float* __restrict__ g,
                                 const float* __restrict__ be,
                                 float* __restrict__ ss, int C){
  const int c = threadIdx.x;
  if (c < C){
    const float invM = 1.f / (float)MROWS;
    const float mean = acc[c] * invM;
    const float var  = acc[C + c] * invM - mean*mean;
    const float scale = g[c] * rsqrtf(var + 1e-5f);
    ss[2*c + 0] = scale;
    ss[2*c + 1] = be[c] - mean * scale;
  }
}

// ---------- Final: normalize+relu h2 (split halves), max over K, write out ----------
__global__ __launch_bounds__(256) void final_kernel(const float* __restrict__ xyz,
                                                    const unsigned* __restrict__ lo,
                                                    const unsigned* __restrict__ hi,
                                                    const float* __restrict__ ss,
                                                    float* __restrict__ out){
  const int q = blockIdx.x * 4 + (threadIdx.x >> 6);
  const int p = threadIdx.x & 63;          // channel pair 0..63 (128 channels)
  const float sc0 = ss[4*p + 0], sh0 = ss[4*p + 1];
  const float sc1 = ss[4*p + 2], sh1 = ss[4*p + 3];
  const unsigned* src = (p < 32) ? (lo + (size_t)q*32*32 + p)
                                 : (hi + (size_t)q*32*32 + (p - 32));
  float m0 = -FLT_MAX_, m1 = -FLT_MAX_;
  #pragma unroll 4
  for (int k = 0; k < 32; ++k){
    unsigned v = src[k*32];
    float a = fmaxf(fmaf(bf2f(v & 0xffffu), sc0, sh0), 0.f);
    float b = fmaxf(fmaf(bf2f(v >> 16),     sc1, sh1), 0.f);
    m0 = fmaxf(m0, a);
    m1 = fmaxf(m1, b);
  }
  float2 r; r.x = m0; r.y = m1;
  ((float2*)(out + (size_t)NB*NQ*3))[(size_t)q*64 + p] = r;
  if (p < 3){
    const int b_ = q >> 10, s = q & 1023;
    out[(size_t)q*3 + p] = xyz[((size_t)b_ * NPTS + s)*3 + p];
  }
}

// ---------- host ----------
extern "C" void kernel_launch(void* const* d_in, const int* in_sizes, int n_in,
                              void* d_out, int out_size, void* d_ws, size_t ws_size,
                              hipStream_t stream){
  (void)in_sizes; (void)n_in; (void)out_size; (void)ws_size;
  const float* xyz = (const float*)d_in[0];
  const float* pts = (const float*)d_in[1];
  const float* W0  = (const float*)d_in[2];
  const float* b0  = (const float*)d_in[3];
  const float* g0  = (const float*)d_in[4];
  const float* be0 = (const float*)d_in[5];
  const float* W1  = (const float*)d_in[6];
  const float* b1  = (const float*)d_in[7];
  const float* g1  = (const float*)d_in[8];
  const float* be1 = (const float*)d_in[9];
  const float* W2  = (const float*)d_in[10];
  const float* b2  = (const float*)d_in[11];
  const float* g2  = (const float*)d_in[12];
  const float* be2 = (const float*)d_in[13];

  // workspace: idx 2MB | acc 512f | ss 512f | h0 64MB (h2-lo later) | h1 64MB (h2-hi later)
  char* ws = (char*)d_ws;
  int*   idx = (int*)ws;
  float* acc = (float*)(ws + 2097152);
  float* ss  = (float*)(ws + 2097152 + 2048);
  unsigned* h0 = (unsigned*)(ws + 2101248);
  unsigned* h1 = (unsigned*)(ws + 2101248 + 67108864);
  float* out = (float*)d_out;

  float* acc0 = acc, *acc1 = acc + 128, *acc2 = acc + 256;   // acc2: 256 floats
  float* ss0 = ss, *ss1 = ss + 128, *ss2 = ss + 256;

  topk_kernel<<<1024, 1024, 0, stream>>>(xyz, idx, acc);
  l0_mfma<<<2048, 256, 0, stream>>>(xyz, pts, idx, W0, b0, (unsigned short*)h0, acc0);
  stats_fin_kernel<<<1, 128, 0, stream>>>(acc0, g0, be0, ss0, 64);
  l12_mfma<4,false><<<2048, 256, 0, stream>>>(h0, ss0, W1, b1, (unsigned short*)h1, nullptr, acc1);
  stats_fin_kernel<<<1, 128, 0, stream>>>(acc1, g1, be1, ss1, 64);
  l12_mfma<8,true><<<2048, 256, 0, stream>>>(h1, ss1, W2, b2, (unsigned short*)h0, (unsigned short*)h1, acc2);
  stats_fin_kernel<<<1, 128, 0, stream>>>(acc2, g2, be2, ss2, 128);
  final_kernel<<<4096, 256, 0, stream>>>(xyz, h0, h1, ss2, out);
}

// Round 5
// 334.833 us; speedup vs baseline: 2.7239x; 1.1069x over previous
//
#include <hip/hip_runtime.h>

#define NPTS 4096
#define NQ   1024     // S
#define NB   16       // B
#define KNN  32
#define MROWS 524288  // B*S*K
#define FLT_MAX_ 3.402823466e+38f

typedef __attribute__((ext_vector_type(8))) short short8;
typedef __attribute__((ext_vector_type(4))) float f32x4;

// ---------- bf16 helpers (manual, RNE) ----------
__device__ inline unsigned short f2bf(float x){
  unsigned u = __float_as_uint(x);
  u += 0x7fffu + ((u >> 16) & 1u);
  return (unsigned short)(u >> 16);
}
__device__ inline float bf2f(unsigned v){           // low 16 bits used
  return __uint_as_float(v << 16);
}

// normalize+relu 8 bf16 (one A-fragment k-slice) -> bf16 frag
__device__ inline short8 norm_frag(uint4 v, const float* sc, const float* sh){
  short8 r;
  const unsigned u[4] = {v.x, v.y, v.z, v.w};
  #pragma unroll
  for (int i = 0; i < 8; ++i){
    const unsigned raw = (i & 1) ? (u[i >> 1] >> 16) : (u[i >> 1] & 0xffffu);
    const float f = fmaxf(fmaf(bf2f(raw), sc[i], sh[i]), 0.f);
    r[i] = (short)f2bf(f);
  }
  return r;
}

// ---------- Kernel 1: top-K=32 NN, one wave/query, f64-packed (d,idx) keys ----------
// key = as_double(d) | j  (low 12 mantissa bits; exact order (d, j)).
// Block 0 also zeroes the stats accumulators (512 floats).
__global__ __launch_bounds__(1024) void topk_kernel(const float* __restrict__ xyz,
                                                    int* __restrict__ idx_out,
                                                    float* __restrict__ statsacc){
  __shared__ float4 pbuf[NPTS];          // x, y, z, |p|^2
  const int tid = threadIdx.x;
  if (blockIdx.x == 0 && tid < 512) statsacc[tid] = 0.f;

  const int b = blockIdx.x >> 6;         // 64 blocks per batch
  const float* xb = xyz + (size_t)b * NPTS * 3;
  for (int p = tid; p < NPTS; p += 1024){
    const float x = xb[3*p + 0], y = xb[3*p + 1], z = xb[3*p + 2];
    pbuf[p] = make_float4(x, y, z, (x*x + y*y) + z*z);
  }
  __syncthreads();

  const int wv   = tid >> 6;
  const int lane = tid & 63;
  const int q    = (blockIdx.x << 4) + wv;
  const int s    = q & (NQ - 1);

  const float4 qp = pbuf[s];
  const float qx = qp.x, qy = qp.y, qz = qp.z, src2 = qp.w;

  const double DINF = __builtin_inf();
  double c0 = DINF, c1 = DINF, c2 = DINF, c3 = DINF;

  // initial scan: all 64 chunks
  for (int e = 0; e < 64; ++e){
    const int j = (e << 6) | lane;
    const float4 pv = pbuf[j];
    const float dot = (qx*pv.x + qy*pv.y) + qz*pv.z;
    const float d = fmaf(dot, -2.f, src2 + pv.w);
    const unsigned long long uu =
        (unsigned long long)__double_as_longlong((double)d) | (unsigned)j;
    const double pd = __longlong_as_double((long long)uu);
    const double t3 = fmin(c3, pd);
    const double n2 = fmin(c2, t3), x3 = fmax(c2, t3);
    const double n1 = fmin(c1, n2), x2 = fmax(c1, n2);
    const double n0 = fmin(c0, n1), x1 = fmax(c0, n1);
    c0 = n0; c1 = x1; c2 = x2; c3 = x3;
  }

  unsigned long long skip = 0ull;   // per-lane consumed chunks (1 point per chunk per lane)
  int ncache = 4;
  int mywin = 0;

  #pragma unroll 1
  for (int it = 0; it < KNN; ++it){
    double w = c0;
    #pragma unroll
    for (int m = 32; m >= 1; m >>= 1)
      w = fmin(w, __shfl_xor(w, m, 64));
    if (lane == it) mywin = (int)((unsigned)__double_as_longlong(w) & 0xFFFu);
    if (c0 == w){                    // unique keys -> exactly one lane
      const unsigned lo = (unsigned)__double_as_longlong(c0);
      skip |= 1ull << ((lo >> 6) & 63u);
      c0 = c1; c1 = c2; c2 = c3; c3 = DINF;
      if (--ncache == 0){
        c0 = c1 = c2 = c3 = DINF;
        for (int e = 0; e < 64; ++e){
          if ((skip >> e) & 1ull) continue;
          const int j = (e << 6) | lane;
          const float4 pv = pbuf[j];
          const float dot = (qx*pv.x + qy*pv.y) + qz*pv.z;
          const float d = fmaf(dot, -2.f, src2 + pv.w);
          const unsigned long long uu =
              (unsigned long long)__double_as_longlong((double)d) | (unsigned)j;
          const double pd = __longlong_as_double((long long)uu);
          const double t3 = fmin(c3, pd);
          const double n2 = fmin(c2, t3), x3 = fmax(c2, t3);
          const double n1 = fmin(c1, n2), x2 = fmax(c1, n2);
          const double n0 = fmin(c0, n1), x1 = fmax(c0, n1);
          c0 = n0; c1 = x1; c2 = x2; c3 = x3;
        }
        ncache = 4;
      }
    }
  }
  if (lane < KNN) idx_out[q * KNN + lane] = mywin;
}

// ---------- Layer 0: gather + concat + MFMA GEMM (K padded 67->96), fused stats ----------
__global__ __launch_bounds__(256) void l0_mfma(const float* __restrict__ xyz,
                                               const float* __restrict__ pts,
                                               const int*   __restrict__ idxbuf,
                                               const float* __restrict__ W,     // (64,67)
                                               const float* __restrict__ bias,  // (64)
                                               unsigned short* __restrict__ hout,
                                               float* __restrict__ acc){
  __shared__ short lds[256*104];
  __shared__ float sacc[128];
  const int tid = threadIdx.x;
  if (tid < 128) sacc[tid] = 0.f;
  const int lane = tid & 63, wv = tid >> 6;
  const int m16 = lane & 15, kg = lane >> 4;

  short8 Bf[4][3];
  float  bl[4];
  for (int ocb = 0; ocb < 4; ++ocb){
    const int n = ocb*16 + m16;
    bl[ocb] = bias[n];
    for (int ks = 0; ks < 3; ++ks){
      short8 t;
      #pragma unroll
      for (int i = 0; i < 8; ++i){
        const int k = ks*32 + kg*8 + i;
        float wv_ = 0.f;
        if (k < 64) wv_ = W[n*67 + 3 + k];
        else if (k < 67) wv_ = W[n*67 + (k - 64)];
        t[i] = (short)f2bf(wv_);
      }
      Bf[ocb][ks] = t;
    }
  }

  {
    const int row = blockIdx.x*256 + tid;
    const int rowq = row >> 5;
    const int b = rowq >> 10, s = rowq & 1023;
    const int j = idxbuf[row];
    const float4* p4 = (const float4*)(pts + ((size_t)b*NPTS + j)*64);
    short* myrow = lds + tid*104;
    #pragma unroll
    for (int u = 0; u < 8; ++u){
      float4 x = p4[2*u], y = p4[2*u+1];
      short8 o;
      o[0]=(short)f2bf(x.x); o[1]=(short)f2bf(x.y); o[2]=(short)f2bf(x.z); o[3]=(short)f2bf(x.w);
      o[4]=(short)f2bf(y.x); o[5]=(short)f2bf(y.y); o[6]=(short)f2bf(y.z); o[7]=(short)f2bf(y.w);
      *(short8*)(myrow + u*8) = o;
    }
    const float* pj = xyz + ((size_t)b*NPTS + j)*3;
    const float* ps = xyz + ((size_t)b*NPTS + s)*3;
    short8 z = 0;
    z[0] = (short)f2bf(pj[0]-ps[0]);
    z[1] = (short)f2bf(pj[1]-ps[1]);
    z[2] = (short)f2bf(pj[2]-ps[2]);
    *(short8*)(myrow + 64) = z;
    short8 zz = 0;
    *(short8*)(myrow + 72) = zz;
    *(short8*)(myrow + 80) = zz;
    *(short8*)(myrow + 88) = zz;
  }
  __syncthreads();

  float sA[4] = {0,0,0,0}, qA[4] = {0,0,0,0};
  const int rowbase = blockIdx.x*256 + wv*64;
  for (int rt = 0; rt < 4; ++rt){
    const short* ar = lds + (wv*64 + rt*16 + m16)*104;
    short8 a0 = *(const short8*)(ar + kg*8);
    short8 a1 = *(const short8*)(ar + 32 + kg*8);
    short8 a2 = *(const short8*)(ar + 64 + kg*8);
    #pragma unroll
    for (int ocb = 0; ocb < 4; ++ocb){
      f32x4 c = {bl[ocb], bl[ocb], bl[ocb], bl[ocb]};
      c = __builtin_amdgcn_mfma_f32_16x16x32_bf16(a0, Bf[ocb][0], c, 0, 0, 0);
      c = __builtin_amdgcn_mfma_f32_16x16x32_bf16(a1, Bf[ocb][1], c, 0, 0, 0);
      c = __builtin_amdgcn_mfma_f32_16x16x32_bf16(a2, Bf[ocb][2], c, 0, 0, 0);
      #pragma unroll
      for (int r = 0; r < 4; ++r){
        const float hv = c[r];
        sA[ocb] += hv; qA[ocb] += hv*hv;
        const int orow = rowbase + rt*16 + kg*4 + r;
        hout[(size_t)orow*64 + ocb*16 + m16] = f2bf(hv);
      }
    }
  }
  #pragma unroll
  for (int ocb = 0; ocb < 4; ++ocb){
    float s = sA[ocb], q = qA[ocb];
    s += __shfl_xor(s, 16, 64); s += __shfl_xor(s, 32, 64);
    q += __shfl_xor(q, 16, 64); q += __shfl_xor(q, 32, 64);
    if (kg == 0){
      atomicAdd(&sacc[ocb*16 + m16], s);
      atomicAdd(&sacc[64 + ocb*16 + m16], q);
    }
  }
  __syncthreads();
  if (tid < 128) atomicAdd(&acc[tid], sacc[tid]);
}

// ---------- Layer 1: norm+relu(A) + MFMA GEMM 64->64, fused stats ----------
__global__ __launch_bounds__(256) void l1_mfma(const unsigned* __restrict__ hin,
                                               const float* __restrict__ ss,    // (64,2)
                                               const float* __restrict__ W,     // (64,64)
                                               const float* __restrict__ bias,  // (64)
                                               unsigned short* __restrict__ hout,
                                               float* __restrict__ acc){
  __shared__ float sacc[128];
  const int tid = threadIdx.x;
  if (tid < 128) sacc[tid] = 0.f;
  const int lane = tid & 63, wv = tid >> 6;
  const int m16 = lane & 15, kg = lane >> 4;

  float scl[2][8], shf[2][8];
  #pragma unroll
  for (int s2 = 0; s2 < 2; ++s2)
    #pragma unroll
    for (int i = 0; i < 8; ++i){
      const int c = s2*32 + kg*8 + i;
      scl[s2][i] = ss[2*c];
      shf[s2][i] = ss[2*c + 1];
    }

  short8 Bf[4][2];
  float  bl[4];
  for (int ocb = 0; ocb < 4; ++ocb){
    const int n = ocb*16 + m16;
    bl[ocb] = bias[n];
    #pragma unroll
    for (int s2 = 0; s2 < 2; ++s2){
      short8 t;
      #pragma unroll
      for (int i = 0; i < 8; ++i)
        t[i] = (short)f2bf(W[n*64 + s2*32 + kg*8 + i]);
      Bf[ocb][s2] = t;
    }
  }
  __syncthreads();

  float sA[4] = {0,0,0,0}, qA[4] = {0,0,0,0};
  const int rowbase = blockIdx.x*256 + wv*64;
  for (int rt = 0; rt < 4; ++rt){
    const int arow = rowbase + rt*16 + m16;
    const uint4* pr = (const uint4*)hin + (size_t)arow*8;
    uint4 v0 = pr[kg];
    uint4 v1 = pr[4 + kg];
    short8 a0 = norm_frag(v0, scl[0], shf[0]);
    short8 a1 = norm_frag(v1, scl[1], shf[1]);
    #pragma unroll
    for (int ocb = 0; ocb < 4; ++ocb){
      f32x4 c = {bl[ocb], bl[ocb], bl[ocb], bl[ocb]};
      c = __builtin_amdgcn_mfma_f32_16x16x32_bf16(a0, Bf[ocb][0], c, 0, 0, 0);
      c = __builtin_amdgcn_mfma_f32_16x16x32_bf16(a1, Bf[ocb][1], c, 0, 0, 0);
      #pragma unroll
      for (int r = 0; r < 4; ++r){
        const float hv = c[r];
        sA[ocb] += hv; qA[ocb] += hv*hv;
        const int orow = rowbase + rt*16 + kg*4 + r;
        hout[(size_t)orow*64 + ocb*16 + m16] = f2bf(hv);
      }
    }
  }
  #pragma unroll
  for (int ocb = 0; ocb < 4; ++ocb){
    float s = sA[ocb], q = qA[ocb];
    s += __shfl_xor(s, 16, 64); s += __shfl_xor(s, 32, 64);
    q += __shfl_xor(q, 16, 64); q += __shfl_xor(q, 32, 64);
    if (kg == 0){
      atomicAdd(&sacc[ocb*16 + m16], s);
      atomicAdd(&sacc[64 + ocb*16 + m16], q);
    }
  }
  __syncthreads();
  if (tid < 128) atomicAdd(&acc[tid], sacc[tid]);
}

// ---------- Layer 2 FUSED: norm+relu(A) + GEMM 64->128 + stats + per-(q,c) max/min ----------
// No h2 materialization: maxpool commutes with the monotone BN+relu epilogue.
__global__ __launch_bounds__(256) void l2_fused(const unsigned* __restrict__ hin,
                                                const float* __restrict__ ss,    // (64,2)
                                                const float* __restrict__ W,     // (128,64)
                                                const float* __restrict__ bias,  // (128)
                                                float* __restrict__ maxb,        // (16384,128)
                                                float* __restrict__ minb,        // (16384,128)
                                                float* __restrict__ acc){
  __shared__ float sacc[256];
  const int tid = threadIdx.x;
  sacc[tid] = 0.f;
  const int lane = tid & 63, wv = tid >> 6;
  const int m16 = lane & 15, kg = lane >> 4;

  float scl[2][8], shf[2][8];
  #pragma unroll
  for (int s2 = 0; s2 < 2; ++s2)
    #pragma unroll
    for (int i = 0; i < 8; ++i){
      const int c = s2*32 + kg*8 + i;
      scl[s2][i] = ss[2*c];
      shf[s2][i] = ss[2*c + 1];
    }

  short8 Bf[8][2];
  float  bl[8];
  for (int ocb = 0; ocb < 8; ++ocb){
    const int n = ocb*16 + m16;
    bl[ocb] = bias[n];
    #pragma unroll
    for (int s2 = 0; s2 < 2; ++s2){
      short8 t;
      #pragma unroll
      for (int i = 0; i < 8; ++i)
        t[i] = (short)f2bf(W[n*64 + s2*32 + kg*8 + i]);
      Bf[ocb][s2] = t;
    }
  }
  __syncthreads();

  float sA[8], qA[8];
  float mx[2][8], mn[2][8];
  #pragma unroll
  for (int o = 0; o < 8; ++o){
    sA[o] = 0.f; qA[o] = 0.f;
    mx[0][o] = -FLT_MAX_; mx[1][o] = -FLT_MAX_;
    mn[0][o] =  FLT_MAX_; mn[1][o] =  FLT_MAX_;
  }

  const int rowbase = blockIdx.x*256 + wv*64;   // 2 queries per wave
  #pragma unroll
  for (int rt = 0; rt < 4; ++rt){
    const int qs = rt >> 1;                     // query select (rows 0-31 / 32-63)
    const int arow = rowbase + rt*16 + m16;
    const uint4* pr = (const uint4*)hin + (size_t)arow*8;
    uint4 v0 = pr[kg];
    uint4 v1 = pr[4 + kg];
    short8 a0 = norm_frag(v0, scl[0], shf[0]);
    short8 a1 = norm_frag(v1, scl[1], shf[1]);
    #pragma unroll
    for (int ocb = 0; ocb < 8; ++ocb){
      f32x4 c = {bl[ocb], bl[ocb], bl[ocb], bl[ocb]};
      c = __builtin_amdgcn_mfma_f32_16x16x32_bf16(a0, Bf[ocb][0], c, 0, 0, 0);
      c = __builtin_amdgcn_mfma_f32_16x16x32_bf16(a1, Bf[ocb][1], c, 0, 0, 0);
      #pragma unroll
      for (int r = 0; r < 4; ++r){
        const float hv = c[r];
        sA[ocb] += hv; qA[ocb] += hv*hv;
        mx[qs][ocb] = fmaxf(mx[qs][ocb], hv);
        mn[qs][ocb] = fminf(mn[qs][ocb], hv);
      }
    }
  }

  // stats reduce
  #pragma unroll
  for (int ocb = 0; ocb < 8; ++ocb){
    float s = sA[ocb], q = qA[ocb];
    s += __shfl_xor(s, 16, 64); s += __shfl_xor(s, 32, 64);
    q += __shfl_xor(q, 16, 64); q += __shfl_xor(q, 32, 64);
    if (kg == 0){
      atomicAdd(&sacc[ocb*16 + m16], s);
      atomicAdd(&sacc[128 + ocb*16 + m16], q);
    }
  }

  // max/min reduce over kg-groups (each lane holds rows kg*4..kg*4+3 per 16-row tile)
  const int qa = rowbase >> 5;
  #pragma unroll
  for (int qs = 0; qs < 2; ++qs)
    #pragma unroll
    for (int ocb = 0; ocb < 8; ++ocb){
      float a = mx[qs][ocb], b = mn[qs][ocb];
      a = fmaxf(a, __shfl_xor(a, 16, 64)); a = fmaxf(a, __shfl_xor(a, 32, 64));
      b = fminf(b, __shfl_xor(b, 16, 64)); b = fminf(b, __shfl_xor(b, 32, 64));
      if (kg == 0){
        maxb[(size_t)(qa + qs)*128 + ocb*16 + m16] = a;
        minb[(size_t)(qa + qs)*128 + ocb*16 + m16] = b;
      }
    }

  __syncthreads();
  atomicAdd(&acc[tid], sacc[tid]);
}

// acc layout: [0..C-1]=sum, [C..2C-1]=sumsq
__global__ void stats_fin_kernel(const float* __restrict__ acc,
                                 const float* __restrict__ g,
                                 const float* __restrict__ be,
                                 float* __restrict__ ss, int C){
  const int c = threadIdx.x;
  if (c < C){
    const float invM = 1.f / (float)MROWS;
    const float mean = acc[c] * invM;
    const float var  = acc[C + c] * invM - mean*mean;
    const float scale = g[c] * rsqrtf(var + 1e-5f);
    ss[2*c + 0] = scale;
    ss[2*c + 1] = be[c] - mean * scale;
  }
}

// ---------- Final: out = relu(scale * (scale>=0 ? max : min) + shift); + new_xyz copy ----------
__global__ __launch_bounds__(256) void final_kernel(const float* __restrict__ xyz,
                                                    const float* __restrict__ maxb,
                                                    const float* __restrict__ minb,
                                                    const float* __restrict__ ss,
                                                    float* __restrict__ out){
  const int q = blockIdx.x * 4 + (threadIdx.x >> 6);
  const int p = threadIdx.x & 63;          // channel pair 0..63 (128 channels)
  const float sc0 = ss[4*p + 0], sh0 = ss[4*p + 1];
  const float sc1 = ss[4*p + 2], sh1 = ss[4*p + 3];
  const float2 mxv = ((const float2*)(maxb + (size_t)q*128))[p];
  const float2 mnv = ((const float2*)(minb + (size_t)q*128))[p];
  const float h0v = (sc0 >= 0.f) ? mxv.x : mnv.x;
  const float h1v = (sc1 >= 0.f) ? mxv.y : mnv.y;
  float2 r;
  r.x = fmaxf(fmaf(sc0, h0v, sh0), 0.f);
  r.y = fmaxf(fmaf(sc1, h1v, sh1), 0.f);
  ((float2*)(out + (size_t)NB*NQ*3))[(size_t)q*64 + p] = r;
  if (p < 3){
    const int b_ = q >> 10, s = q & 1023;
    out[(size_t)q*3 + p] = xyz[((size_t)b_ * NPTS + s)*3 + p];
  }
}

// ---------- host ----------
extern "C" void kernel_launch(void* const* d_in, const int* in_sizes, int n_in,
                              void* d_out, int out_size, void* d_ws, size_t ws_size,
                              hipStream_t stream){
  (void)in_sizes; (void)n_in; (void)out_size; (void)ws_size;
  const float* xyz = (const float*)d_in[0];
  const float* pts = (const float*)d_in[1];
  const float* W0  = (const float*)d_in[2];
  const float* b0  = (const float*)d_in[3];
  const float* g0  = (const float*)d_in[4];
  const float* be0 = (const float*)d_in[5];
  const float* W1  = (const float*)d_in[6];
  const float* b1  = (const float*)d_in[7];
  const float* g1  = (const float*)d_in[8];
  const float* be1 = (const float*)d_in[9];
  const float* W2  = (const float*)d_in[10];
  const float* b2  = (const float*)d_in[11];
  const float* g2  = (const float*)d_in[12];
  const float* be2 = (const float*)d_in[13];

  // workspace: idx 2MB | acc 512f | ss 512f | h0 64MB | h1 64MB  (~130 MB)
  // max/min buffers (8MB each) reuse the h0 region (dead after l1).
  char* ws = (char*)d_ws;
  int*   idx = (int*)ws;
  float* acc = (float*)(ws + 2097152);
  float* ss  = (float*)(ws + 2097152 + 2048);
  unsigned* h0 = (unsigned*)(ws + 2101248);
  unsigned* h1 = (unsigned*)(ws + 2101248 + 67108864);
  float* maxb = (float*)h0;
  float* minb = maxb + (size_t)16384*128;
  float* out = (float*)d_out;

  float* acc0 = acc, *acc1 = acc + 128, *acc2 = acc + 256;   // acc2: 256 floats
  float* ss0 = ss, *ss1 = ss + 128, *ss2 = ss + 256;

  topk_kernel<<<1024, 1024, 0, stream>>>(xyz, idx, acc);
  l0_mfma<<<2048, 256, 0, stream>>>(xyz, pts, idx, W0, b0, (unsigned short*)h0, acc0);
  stats_fin_kernel<<<1, 128, 0, stream>>>(acc0, g0, be0, ss0, 64);
  l1_mfma<<<2048, 256, 0, stream>>>(h0, ss0, W1, b1, (unsigned short*)h1, acc1);
  stats_fin_kernel<<<1, 128, 0, stream>>>(acc1, g1, be1, ss1, 64);
  l2_fused<<<2048, 256, 0, stream>>>(h1, ss1, W2, b2, maxb, minb, acc2);
  stats_fin_kernel<<<1, 128, 0, stream>>>(acc2, g2, be2, ss2, 128);
  final_kernel<<<4096, 256, 0, stream>>>(xyz, maxb, minb, ss2, out);
}